// Round 5
// baseline (434.017 us; speedup 1.0000x reference)
//
#include <hip/hip_runtime.h>
#include <hip/hip_bf16.h>

// Problem constants
#define N_ 64
#define C_ 64
#define T_ 300
#define V_ 25
#define K_ 3
#define TT 6              // t-values per block
#define NTILE 50          // T_/TT
#define NBLK 3200         // N_ * NTILE
#define XROW 192          // xs row pitch in elems: TT*32 (bank-neutral: 384B % 128B == 0)
#define EPS_ 1e-5f

typedef __bf16 bf16_t;
typedef __bf16 bf16x8 __attribute__((ext_vector_type(8)));
typedef float f32x4 __attribute__((ext_vector_type(4)));
typedef float f32x4u __attribute__((ext_vector_type(4), aligned(4)));

static __device__ __forceinline__ bf16_t tobf(float f) { return (bf16_t)f; }
// element-index swizzle within a c-row: spreads b128 reads uniformly over banks
static __device__ __forceinline__ int emask(int c) { return ((c & 3) << 3) | ((c & 8) << 2); }

// ---------------------------------------------------------------------------
// K1: y[n,o,t,w] = sum_k sum_c W[k,o,c] * (sum_v x[n,c,t,v] A[k,v,w]) + bsum[o]
// Register-chained MFMA (stage-A D feeds stage-B B-operand; verified in R3),
// fed from an LDS-staged x tile with coalesced global loads + bank swizzle.
// Block = (n, 6 t's); wave wv owns output rows o = wv*16..+15.
// ---------------------------------------------------------------------------
__global__ __launch_bounds__(256, 6) void k1_compute(
    const float* __restrict__ x, const float* __restrict__ A,
    const float* __restrict__ W, const float* __restrict__ b,
    float* __restrict__ y, float* __restrict__ pSum, float* __restrict__ pSqs) {
  __shared__ __align__(16) bf16_t xs[64 * XROW];   // [c][ ((t<<5)+v) ^ emask(c) ]
  __shared__ float stats[2][64];

  // XCD-bijective swizzle: 3200 = 8 * 400; bid = xcd*400 + idx (ADD, not OR --
  // 400 is not a power of two, OR on overlapping bits was R4's correctness bug)
  const int bid = (blockIdx.x & 7) * (NBLK / 8) + (blockIdx.x >> 3);
  const int n = bid / NTILE;
  const int t0 = (bid - n * NTILE) * TT;
  const int tid = threadIdx.x;
  const int lane = tid & 63;
  const int wv = tid >> 6;        // wave 0..3 -> o-block
  const int l15 = lane & 15;
  const int lg = lane >> 4;       // 0..3

  // --- W fragments (stage-B A-operand): row=l15 -> o, k-slot lg*8+j -> kc.
  bf16x8 wfrag[6];
  {
    const int o = wv * 16 + l15;
    #pragma unroll
    for (int k = 0; k < 3; ++k)
      #pragma unroll
      for (int ch = 0; ch < 2; ++ch) {
        const float* wp = W + ((k * 64 + o) * 64 + ch * 32 + lg * 8);
        f32x4u a = *reinterpret_cast<const f32x4u*>(wp);
        f32x4u c4 = *reinterpret_cast<const f32x4u*>(wp + 4);
        bf16x8 f;
        f[0] = tobf(a[0]); f[1] = tobf(a[1]); f[2] = tobf(a[2]); f[3] = tobf(a[3]);
        f[4] = tobf(c4[0]); f[5] = tobf(c4[1]); f[6] = tobf(c4[2]); f[7] = tobf(c4[3]);
        wfrag[k * 2 + ch] = f;
      }
  }
  // --- A-matrix fragments (stage-A B-operand): Ak[v][w], v,w padded 25->32 (zeros)
  bf16x8 afrag[3][2];
  #pragma unroll
  for (int k = 0; k < 3; ++k)
    #pragma unroll
    for (int wh = 0; wh < 2; ++wh) {
      int w = wh * 16 + l15;
      bf16x8 f;
      #pragma unroll
      for (int j = 0; j < 8; ++j) {
        int v = lg * 8 + j;
        float val = (v < V_ && w < V_) ? A[(k * V_ + v) * V_ + w] : 0.f;
        f[j] = tobf(val);
      }
      afrag[k][wh] = f;
    }

  // --- zero the v-pads (v=25..31 per (c,t))
  for (int i = tid; i < 64 * TT * 7; i += 256) {
    int c = i / (TT * 7);
    int r = i - c * (TT * 7);
    int t = r / 7, v = 25 + (r - t * 7);
    xs[c * XROW + (((t << 5) + v) ^ emask(c))] = tobf(0.f);
  }
  // --- coalesced x load -> xs. Per c: 150 contiguous floats (6 t-rows), 8B-aligned.
  {
    const float* xb = x + (size_t)n * 480000 + (size_t)t0 * 25;
    for (int m = tid; m < 64 * 75; m += 256) {
      int c = m / 75, p = m - c * 75;
      float2 fv = *reinterpret_cast<const float2*>(xb + (size_t)c * 7500 + 2 * p);
      int e = 2 * p;
      int t = e / 25, v = e - t * 25;
      int t1 = t, v1 = v + 1;
      if (v1 == 25) { v1 = 0; t1 = t + 1; }
      int em = emask(c);
      xs[c * XROW + (((t  << 5) + v ) ^ em)] = tobf(fv.x);
      xs[c * XROW + (((t1 << 5) + v1) ^ em)] = tobf(fv.y);
    }
  }
  __syncthreads();

  // --- per-lane fragment LDS offsets. Permuted c-map (R3-verified):
  // frag q=(chalf,sub): c = chalf*32 + sub*4 + 8*(l15>>2) + (l15&3)
  const int crow = 8 * (l15 >> 2) + (l15 & 3);
  int fK[4], fS5[4];
  #pragma unroll
  for (int q = 0; q < 4; ++q) {
    int c = ((q >> 1) * 32) + ((q & 1) * 4) + crow;
    int em = emask(c);
    fK[q] = c * XROW + ((lg * 8) ^ (em & 24));
    fS5[q] = em & 32;
  }

  const int obase = wv * 16 + lg * 4;      // lane's 4 output rows: obase+r
  float bs[4];
  #pragma unroll
  for (int r = 0; r < 4; ++r)
    bs[r] = b[obase + r] + b[64 + obase + r] + b[128 + obase + r];

  float lsum[4] = {0.f,0.f,0.f,0.f}, lsq[4] = {0.f,0.f,0.f,0.f};
  float* yb = y + (size_t)n * 480000 + (size_t)t0 * 25;
  const int w_lo = l15;
  const int w_hi = 16 + l15;

  #pragma unroll 1
  for (int t = 0; t < TT; ++t) {
    bf16x8 xf[4];
    #pragma unroll
    for (int q = 0; q < 4; ++q)
      xf[q] = *reinterpret_cast<const bf16x8*>(xs + fK[q] + (((t << 5) ^ fS5[q])));

    #pragma unroll
    for (int wh = 0; wh < 2; ++wh) {
      f32x4 acc0 = {0.f,0.f,0.f,0.f}, acc1 = {0.f,0.f,0.f,0.f};
      #pragma unroll
      for (int k = 0; k < 3; ++k) {
        #pragma unroll
        for (int ch = 0; ch < 2; ++ch) {
          f32x4 zero = {0.f,0.f,0.f,0.f};
          f32x4 dP = __builtin_amdgcn_mfma_f32_16x16x32_bf16(xf[ch*2+0], afrag[k][wh], zero, 0, 0, 0);
          f32x4 dQ = __builtin_amdgcn_mfma_f32_16x16x32_bf16(xf[ch*2+1], afrag[k][wh], zero, 0, 0, 0);
          bf16x8 zf;
          zf[0] = tobf(dP[0]); zf[1] = tobf(dP[1]); zf[2] = tobf(dP[2]); zf[3] = tobf(dP[3]);
          zf[4] = tobf(dQ[0]); zf[5] = tobf(dQ[1]); zf[6] = tobf(dQ[2]); zf[7] = tobf(dQ[3]);
          if (ch == 0)
            acc0 = __builtin_amdgcn_mfma_f32_16x16x32_bf16(wfrag[k*2+ch], zf, acc0, 0, 0, 0);
          else
            acc1 = __builtin_amdgcn_mfma_f32_16x16x32_bf16(wfrag[k*2+ch], zf, acc1, 0, 0, 0);
        }
      }
      const int w = wh ? w_hi : w_lo;
      if (w < V_) {
        #pragma unroll
        for (int r = 0; r < 4; ++r) {
          float val = acc0[r] + acc1[r] + bs[r];
          lsum[r] += val;
          lsq[r] += val * val;
          yb[(size_t)(obase + r) * 7500 + t * 25 + w] = val;
        }
      }
    }
  }

  // reduce across the 16 lanes (l15) that share the same 4 o-rows
  #pragma unroll
  for (int d = 1; d < 16; d <<= 1) {
    #pragma unroll
    for (int r = 0; r < 4; ++r) {
      lsum[r] += __shfl_xor(lsum[r], d);
      lsq[r]  += __shfl_xor(lsq[r], d);
    }
  }
  if (l15 == 0) {
    #pragma unroll
    for (int r = 0; r < 4; ++r) {
      stats[0][obase + r] = lsum[r];
      stats[1][obase + r] = lsq[r];
    }
  }
  __syncthreads();
  if (tid < 64)        pSum[(size_t)tid * NBLK + bid] = stats[0][tid];
  else if (tid < 128)  pSqs[(size_t)(tid - 64) * NBLK + bid] = stats[1][tid - 64];
}

// ---------------------------------------------------------------------------
// K2: reduce partials -> per-channel scale/shift
// ---------------------------------------------------------------------------
__global__ __launch_bounds__(256) void k2_stats(
    const float* __restrict__ pSum, const float* __restrict__ pSqs,
    const float* __restrict__ gamma, const float* __restrict__ beta,
    float* __restrict__ ss) {
  const int o = blockIdx.x;
  const int tid = threadIdx.x;
  double s = 0.0, q = 0.0;
  for (int i = tid; i < NBLK; i += 256) {
    s += (double)pSum[(size_t)o * NBLK + i];
    q += (double)pSqs[(size_t)o * NBLK + i];
  }
  __shared__ double sd[256], qd[256];
  sd[tid] = s; qd[tid] = q;
  __syncthreads();
  for (int step = 128; step > 0; step >>= 1) {
    if (tid < step) { sd[tid] += sd[tid + step]; qd[tid] += qd[tid + step]; }
    __syncthreads();
  }
  if (tid == 0) {
    const double cnt = 480000.0;
    double mean = sd[0] / cnt;
    double var = qd[0] / cnt - mean * mean;
    float inv = rsqrtf((float)var + EPS_);
    float sc = gamma[o] * inv;
    float sh = beta[o] - (float)mean * sc;
    ss[2 * o] = sc;
    ss[2 * o + 1] = sh;
  }
}

// ---------------------------------------------------------------------------
// K3: out = relu(scale[c]*y + shift[c] + x), in place on d_out (y staged there).
// ---------------------------------------------------------------------------
__global__ __launch_bounds__(256) void k3_finish(
    const float* __restrict__ x, const float* __restrict__ ss,
    float* __restrict__ y) {
  const int p = blockIdx.x;       // 0..4095 = n*64 + c
  const int c = p & 63;
  const float sc = ss[2 * c];
  const float sh = ss[2 * c + 1];
  const float4* xv = reinterpret_cast<const float4*>(x + (size_t)p * 7500);
  float4* yv = reinterpret_cast<float4*>(y + (size_t)p * 7500);
  for (int i = threadIdx.x; i < 1875; i += 256) {
    float4 a = yv[i];
    float4 b4 = xv[i];
    float4 o;
    o.x = fmaxf(sc * a.x + sh + b4.x, 0.f);
    o.y = fmaxf(sc * a.y + sh + b4.y, 0.f);
    o.z = fmaxf(sc * a.z + sh + b4.z, 0.f);
    o.w = fmaxf(sc * a.w + sh + b4.w, 0.f);
    yv[i] = o;
  }
}

extern "C" void kernel_launch(void* const* d_in, const int* in_sizes, int n_in,
                              void* d_out, int out_size, void* d_ws, size_t ws_size,
                              hipStream_t stream) {
  const float* x     = (const float*)d_in[0];
  const float* A     = (const float*)d_in[1];
  const float* W     = (const float*)d_in[2];
  const float* b     = (const float*)d_in[3];
  const float* gamma = (const float*)d_in[4];
  const float* beta  = (const float*)d_in[5];
  float* y = (float*)d_out;                  // stage y in d_out, finish in place

  float* pSum = (float*)d_ws;                // 64*NBLK floats
  float* pSqs = pSum + 64 * NBLK;            // 64*NBLK floats
  float* ss   = pSqs + 64 * NBLK;            // 128 floats

  k1_compute<<<NBLK, 256, 0, stream>>>(x, A, W, b, y, pSum, pSqs);
  k2_stats<<<64, 256, 0, stream>>>(pSum, pSqs, gamma, beta, ss);
  k3_finish<<<4096, 256, 0, stream>>>(x, ss, y);
}

// Round 6
// 218.500 us; speedup vs baseline: 1.9863x; 1.9863x over previous
//
#include <hip/hip_runtime.h>
#include <hip/hip_bf16.h>

// Problem constants
#define N_ 64
#define C_ 64
#define T_ 300
#define V_ 25
#define K_ 3
#define TT 6              // t-values per block
#define NTILE 50          // T_/TT
#define NBLK 3200         // N_ * NTILE
#define XROW 192          // xs row pitch in elems: TT*32 (bank-neutral: 384B % 128B == 0)
#define EPS_ 1e-5f

typedef __bf16 bf16_t;
typedef __bf16 bf16x8 __attribute__((ext_vector_type(8)));
typedef float f32x4 __attribute__((ext_vector_type(4)));
typedef float f32x4u __attribute__((ext_vector_type(4), aligned(4)));

static __device__ __forceinline__ bf16_t tobf(float f) { return (bf16_t)f; }
// element-index swizzle within a c-row: spreads b128 reads uniformly over banks
static __device__ __forceinline__ int emask(int c) { return ((c & 3) << 3) | ((c & 8) << 2); }

// ===========================================================================
// Shared device helpers: prologue (fragment setup + LDS staging) for both
// passes. y[n,o,t,w] = sum_k sum_c W[k,o,c] * (sum_v x[n,c,t,v] A[k,v,w]) + bsum[o]
// Register-chained MFMA: stage-A D feeds stage-B B-operand (R3/R5-verified).
// ===========================================================================
struct Frags {
  bf16x8 wfrag[6];
  bf16x8 afrag[3][2];
  int fK[4], fS5[4];
  float bs[4];
  int obase;
};

static __device__ __forceinline__ void setup_frags(
    const float* __restrict__ A, const float* __restrict__ W,
    const float* __restrict__ b, int wv, int l15, int lg, Frags& F) {
  // W fragments (stage-B A-operand): row=l15 -> o, k-slot lg*8+j -> kc
  {
    const int o = wv * 16 + l15;
    #pragma unroll
    for (int k = 0; k < 3; ++k)
      #pragma unroll
      for (int ch = 0; ch < 2; ++ch) {
        const float* wp = W + ((k * 64 + o) * 64 + ch * 32 + lg * 8);
        f32x4u a = *reinterpret_cast<const f32x4u*>(wp);
        f32x4u c4 = *reinterpret_cast<const f32x4u*>(wp + 4);
        bf16x8 f;
        f[0] = tobf(a[0]); f[1] = tobf(a[1]); f[2] = tobf(a[2]); f[3] = tobf(a[3]);
        f[4] = tobf(c4[0]); f[5] = tobf(c4[1]); f[6] = tobf(c4[2]); f[7] = tobf(c4[3]);
        F.wfrag[k * 2 + ch] = f;
      }
  }
  // A-matrix fragments (stage-A B-operand): Ak[v][w], v,w padded 25->32 (zeros)
  #pragma unroll
  for (int k = 0; k < 3; ++k)
    #pragma unroll
    for (int wh = 0; wh < 2; ++wh) {
      int w = wh * 16 + l15;
      bf16x8 f;
      #pragma unroll
      for (int j = 0; j < 8; ++j) {
        int v = lg * 8 + j;
        float val = (v < V_ && w < V_) ? A[(k * V_ + v) * V_ + w] : 0.f;
        f[j] = tobf(val);
      }
      F.afrag[k][wh] = f;
    }
  // per-lane fragment LDS offsets. Permuted c-map:
  // frag q=(chalf,sub): c = chalf*32 + sub*4 + 8*(l15>>2) + (l15&3)
  const int crow = 8 * (l15 >> 2) + (l15 & 3);
  #pragma unroll
  for (int q = 0; q < 4; ++q) {
    int c = ((q >> 1) * 32) + ((q & 1) * 4) + crow;
    int em = emask(c);
    F.fK[q] = c * XROW + ((lg * 8) ^ (em & 24));
    F.fS5[q] = em & 32;
  }
  F.obase = wv * 16 + lg * 4;
  #pragma unroll
  for (int r = 0; r < 4; ++r)
    F.bs[r] = b[F.obase + r] + b[64 + F.obase + r] + b[128 + F.obase + r];
}

static __device__ __forceinline__ void stage_x(
    const float* __restrict__ x, bf16_t* xs, int n, int t0, int tid) {
  // zero the v-pads (v=25..31 per (c,t))
  for (int i = tid; i < 64 * TT * 7; i += 256) {
    int c = i / (TT * 7);
    int r = i - c * (TT * 7);
    int t = r / 7, v = 25 + (r - t * 7);
    xs[c * XROW + (((t << 5) + v) ^ emask(c))] = tobf(0.f);
  }
  // coalesced x load. Per c: 150 contiguous floats (6 t-rows), 8B-aligned.
  const float* xb = x + (size_t)n * 480000 + (size_t)t0 * 25;
  for (int m = tid; m < 64 * 75; m += 256) {
    int c = m / 75, p = m - c * 75;
    float2 fv = *reinterpret_cast<const float2*>(xb + (size_t)c * 7500 + 2 * p);
    int e = 2 * p;
    int t = e / 25, v = e - t * 25;
    int t1 = t, v1 = v + 1;
    if (v1 == 25) { v1 = 0; t1 = t + 1; }
    int em = emask(c);
    xs[c * XROW + (((t  << 5) + v ) ^ em)] = tobf(fv.x);
    xs[c * XROW + (((t1 << 5) + v1) ^ em)] = tobf(fv.y);
  }
}

// compute one t's two half-accumulators for a wave (acc0+acc1 summed later)
static __device__ __forceinline__ void compute_t(
    const bf16_t* xs, const Frags& F, int t, int wh, f32x4& acc0, f32x4& acc1) {
  bf16x8 xf[4];
  #pragma unroll
  for (int q = 0; q < 4; ++q)
    xf[q] = *reinterpret_cast<const bf16x8*>(xs + F.fK[q] + ((t << 5) ^ F.fS5[q]));
  acc0 = f32x4{0.f,0.f,0.f,0.f};
  acc1 = f32x4{0.f,0.f,0.f,0.f};
  #pragma unroll
  for (int k = 0; k < 3; ++k) {
    #pragma unroll
    for (int ch = 0; ch < 2; ++ch) {
      f32x4 zero = {0.f,0.f,0.f,0.f};
      f32x4 dP = __builtin_amdgcn_mfma_f32_16x16x32_bf16(xf[ch*2+0], F.afrag[k][wh], zero, 0, 0, 0);
      f32x4 dQ = __builtin_amdgcn_mfma_f32_16x16x32_bf16(xf[ch*2+1], F.afrag[k][wh], zero, 0, 0, 0);
      bf16x8 zf;
      zf[0] = tobf(dP[0]); zf[1] = tobf(dP[1]); zf[2] = tobf(dP[2]); zf[3] = tobf(dP[3]);
      zf[4] = tobf(dQ[0]); zf[5] = tobf(dQ[1]); zf[6] = tobf(dQ[2]); zf[7] = tobf(dQ[3]);
      if (ch == 0)
        acc0 = __builtin_amdgcn_mfma_f32_16x16x32_bf16(F.wfrag[k*2+ch], zf, acc0, 0, 0, 0);
      else
        acc1 = __builtin_amdgcn_mfma_f32_16x16x32_bf16(F.wfrag[k*2+ch], zf, acc1, 0, 0, 0);
    }
  }
}

// ---------------------------------------------------------------------------
// K1: stats-only pass. No y store (k3 recomputes). Partial sum/sumsq per block.
// ---------------------------------------------------------------------------
__global__ __launch_bounds__(256, 4) void k1_stats(
    const float* __restrict__ x, const float* __restrict__ A,
    const float* __restrict__ W, const float* __restrict__ b,
    float* __restrict__ pSum, float* __restrict__ pSqs) {
  __shared__ __align__(16) bf16_t xs[64 * XROW];
  __shared__ float stats[2][64];

  const int bid = (blockIdx.x & 7) * (NBLK / 8) + (blockIdx.x >> 3);  // bijective
  const int n = bid / NTILE;
  const int t0 = (bid - n * NTILE) * TT;
  const int tid = threadIdx.x;
  const int lane = tid & 63;
  const int wv = tid >> 6;
  const int l15 = lane & 15;
  const int lg = lane >> 4;

  Frags F;
  setup_frags(A, W, b, wv, l15, lg, F);
  stage_x(x, xs, n, t0, tid);
  __syncthreads();

  float lsum[4] = {0.f,0.f,0.f,0.f}, lsq[4] = {0.f,0.f,0.f,0.f};
  const int w_lo = l15, w_hi = 16 + l15;

  #pragma unroll 1
  for (int t = 0; t < TT; ++t) {
    #pragma unroll
    for (int wh = 0; wh < 2; ++wh) {
      f32x4 acc0, acc1;
      compute_t(xs, F, t, wh, acc0, acc1);
      const int w = wh ? w_hi : w_lo;
      if (w < V_) {
        #pragma unroll
        for (int r = 0; r < 4; ++r) {
          float val = acc0[r] + acc1[r] + F.bs[r];
          lsum[r] += val;
          lsq[r] += val * val;
        }
      }
    }
  }

  #pragma unroll
  for (int d = 1; d < 16; d <<= 1) {
    #pragma unroll
    for (int r = 0; r < 4; ++r) {
      lsum[r] += __shfl_xor(lsum[r], d);
      lsq[r]  += __shfl_xor(lsq[r], d);
    }
  }
  if (l15 == 0) {
    #pragma unroll
    for (int r = 0; r < 4; ++r) {
      stats[0][F.obase + r] = lsum[r];
      stats[1][F.obase + r] = lsq[r];
    }
  }
  __syncthreads();
  if (tid < 64)        pSum[(size_t)tid * NBLK + bid] = stats[0][tid];
  else if (tid < 128)  pSqs[(size_t)(tid - 64) * NBLK + bid] = stats[1][tid - 64];
}

// ---------------------------------------------------------------------------
// K2: reduce partials -> per-channel scale/shift
// ---------------------------------------------------------------------------
__global__ __launch_bounds__(256) void k2_stats(
    const float* __restrict__ pSum, const float* __restrict__ pSqs,
    const float* __restrict__ gamma, const float* __restrict__ beta,
    float* __restrict__ ss) {
  const int o = blockIdx.x;
  const int tid = threadIdx.x;
  double s = 0.0, q = 0.0;
  for (int i = tid; i < NBLK; i += 256) {
    s += (double)pSum[(size_t)o * NBLK + i];
    q += (double)pSqs[(size_t)o * NBLK + i];
  }
  __shared__ double sd[256], qd[256];
  sd[tid] = s; qd[tid] = q;
  __syncthreads();
  for (int step = 128; step > 0; step >>= 1) {
    if (tid < step) { sd[tid] += sd[tid + step]; qd[tid] += qd[tid + step]; }
    __syncthreads();
  }
  if (tid == 0) {
    const double cnt = 480000.0;
    double mean = sd[0] / cnt;
    double var = qd[0] / cnt - mean * mean;
    float inv = rsqrtf((float)var + EPS_);
    float sc = gamma[o] * inv;
    float sh = beta[o] - (float)mean * sc;
    ss[2 * o] = sc;
    ss[2 * o + 1] = sh;
  }
}

// ---------------------------------------------------------------------------
// K3: recompute y, apply BN + residual (x from LDS, bf16) + relu, store out.
// ---------------------------------------------------------------------------
__global__ __launch_bounds__(256, 4) void k3_apply(
    const float* __restrict__ x, const float* __restrict__ A,
    const float* __restrict__ W, const float* __restrict__ b,
    const float* __restrict__ ss, float* __restrict__ out) {
  __shared__ __align__(16) bf16_t xs[64 * XROW];

  const int bid = (blockIdx.x & 7) * (NBLK / 8) + (blockIdx.x >> 3);  // bijective
  const int n = bid / NTILE;
  const int t0 = (bid - n * NTILE) * TT;
  const int tid = threadIdx.x;
  const int lane = tid & 63;
  const int wv = tid >> 6;
  const int l15 = lane & 15;
  const int lg = lane >> 4;

  Frags F;
  setup_frags(A, W, b, wv, l15, lg, F);
  stage_x(x, xs, n, t0, tid);

  float sc[4], sh[4];
  #pragma unroll
  for (int r = 0; r < 4; ++r) {
    sc[r] = ss[2 * (F.obase + r)];
    sh[r] = ss[2 * (F.obase + r) + 1];
  }
  __syncthreads();

  float* ob = out + (size_t)n * 480000 + (size_t)t0 * 25;
  const int w_lo = l15, w_hi = 16 + l15;

  #pragma unroll 1
  for (int t = 0; t < TT; ++t) {
    #pragma unroll
    for (int wh = 0; wh < 2; ++wh) {
      f32x4 acc0, acc1;
      compute_t(xs, F, t, wh, acc0, acc1);
      const int w = wh ? w_hi : w_lo;
      if (w < V_) {
        #pragma unroll
        for (int r = 0; r < 4; ++r) {
          const int o = F.obase + r;
          float val = acc0[r] + acc1[r] + F.bs[r];
          float xr = (float)xs[o * XROW + (((t << 5) + w) ^ emask(o))];
          ob[(size_t)o * 7500 + t * 25 + w] = fmaxf(sc[r] * val + sh[r] + xr, 0.f);
        }
      }
    }
  }
}

extern "C" void kernel_launch(void* const* d_in, const int* in_sizes, int n_in,
                              void* d_out, int out_size, void* d_ws, size_t ws_size,
                              hipStream_t stream) {
  const float* x     = (const float*)d_in[0];
  const float* A     = (const float*)d_in[1];
  const float* W     = (const float*)d_in[2];
  const float* b     = (const float*)d_in[3];
  const float* gamma = (const float*)d_in[4];
  const float* beta  = (const float*)d_in[5];
  float* out = (float*)d_out;

  float* pSum = (float*)d_ws;                // 64*NBLK floats
  float* pSqs = pSum + 64 * NBLK;            // 64*NBLK floats
  float* ss   = pSqs + 64 * NBLK;            // 128 floats

  k1_stats<<<NBLK, 256, 0, stream>>>(x, A, W, b, pSum, pSqs);
  k2_stats<<<64, 256, 0, stream>>>(pSum, pSqs, gamma, beta, ss);
  k3_apply<<<NBLK, 256, 0, stream>>>(x, A, W, b, ss, out);
}

// Round 7
// 147.804 us; speedup vs baseline: 2.9364x; 1.4783x over previous
//
#include <hip/hip_runtime.h>
#include <hip/hip_bf16.h>

// Problem constants
#define N_ 64
#define C_ 64
#define T_ 300
#define V_ 25
#define K_ 3
#define TT 12             // t-values per block
#define NTILE 25          // T_/TT
#define NBLK 1600         // N_ * NTILE
#define XROW 384          // xs row pitch in elems: TT*32 (768B rows, bank-neutral)
#define WP 72             // W-lds row pitch (144B -> conflict-free b128 frag reads)
#define AP 33             // A-lds row pitch
#define EPS_ 1e-5f

typedef __bf16 bf16_t;
typedef __bf16 bf16x4 __attribute__((ext_vector_type(4)));
typedef __bf16 bf16x8 __attribute__((ext_vector_type(8)));
typedef float f32x4 __attribute__((ext_vector_type(4)));

static __device__ __forceinline__ bf16_t tobf(float f) { return (bf16_t)f; }
// element-index swizzle within a c-row: spreads b128 reads uniformly over banks
static __device__ __forceinline__ int emask(int c) { return ((c & 3) << 3) | ((c & 8) << 2); }

// Shared-memory overlay: W/A staging (prologue only) reuses the xs region.
union SmemU {
  struct { bf16_t W[3 * 64 * WP]; bf16_t A[3 * 32 * AP + 8]; } wa;
  bf16_t xs[64 * XROW];
};

struct Frags {
  bf16x8 wfrag[6];
  bf16x8 afrag[3][2];
  int fK[4], fS5[4];
  float bs[4];
  int obase;
};

// ---- coalesced W/A global->LDS staging (bf16), then fragment reads from LDS
static __device__ __forceinline__ void stage_wa(
    const float* __restrict__ A, const float* __restrict__ W, SmemU& sm, int tid) {
  // W: 12288 floats = 3072 float4, [k][o][c] rows of 64 (float4 never crosses a row)
  for (int m = tid; m < 3072; m += 256) {
    f32x4 v4 = *(reinterpret_cast<const f32x4*>(W) + m);
    int f = m << 2;
    int k = f >> 12, o = (f >> 6) & 63, c = f & 63;
    bf16x4 h;
    h[0] = tobf(v4[0]); h[1] = tobf(v4[1]); h[2] = tobf(v4[2]); h[3] = tobf(v4[3]);
    *reinterpret_cast<bf16x4*>(&sm.wa.W[(k * 64 + o) * WP + c]) = h;
  }
  // A: 1875 floats, [k][v][w] rows of 25
  for (int f = tid; f < 1875; f += 256) {
    int k = f / 625, r = f - k * 625;
    int v = r / 25, w = r - v * 25;
    sm.wa.A[(k * 32 + v) * AP + w] = tobf(A[f]);
  }
}

static __device__ __forceinline__ void read_frags(
    const SmemU& sm, const float* __restrict__ b, int wv, int l15, int lg, Frags& F) {
  const int o = wv * 16 + l15;
  #pragma unroll
  for (int k = 0; k < 3; ++k)
    #pragma unroll
    for (int ch = 0; ch < 2; ++ch)
      F.wfrag[k * 2 + ch] =
          *reinterpret_cast<const bf16x8*>(&sm.wa.W[(k * 64 + o) * WP + ch * 32 + lg * 8]);
  #pragma unroll
  for (int k = 0; k < 3; ++k)
    #pragma unroll
    for (int wh = 0; wh < 2; ++wh) {
      int w = wh * 16 + l15;
      bf16x8 f;
      #pragma unroll
      for (int j = 0; j < 8; ++j) {
        int v = lg * 8 + j;
        bf16_t val = sm.wa.A[(k * 32 + v) * AP + w];   // in-bounds; masked below
        f[j] = (v < V_ && w < V_) ? val : tobf(0.f);
      }
      F.afrag[k][wh] = f;
    }
  // per-lane fragment LDS offsets. Permuted c-map (R3/R6-verified):
  // frag q=(chalf,sub): c = chalf*32 + sub*4 + 8*(l15>>2) + (l15&3)
  const int crow = 8 * (l15 >> 2) + (l15 & 3);
  #pragma unroll
  for (int q = 0; q < 4; ++q) {
    int c = ((q >> 1) * 32) + ((q & 1) * 4) + crow;
    int em = emask(c);
    F.fK[q] = c * XROW + ((lg * 8) ^ (em & 24));
    F.fS5[q] = em & 32;
  }
  F.obase = wv * 16 + lg * 4;
  #pragma unroll
  for (int r = 0; r < 4; ++r)
    F.bs[r] = b[F.obase + r] + b[64 + F.obase + r] + b[128 + F.obase + r];
}

static __device__ __forceinline__ void stage_x(
    const float* __restrict__ x, SmemU& sm, int n, int t0, int tid) {
  // zero the v-pads (v=25..31 per (c,t))
  for (int i = tid; i < 64 * TT * 7; i += 256) {
    int c = i / (TT * 7);
    int r = i - c * (TT * 7);
    int t = r / 7, v = 25 + (r - t * 7);
    sm.xs[c * XROW + (((t << 5) + v) ^ emask(c))] = tobf(0.f);
  }
  // coalesced x load: per c-row 300 contiguous floats = 75 float4 (16B aligned)
  const float* xb = x + (size_t)n * 480000 + (size_t)t0 * 25;
  for (int m = tid; m < 4800; m += 256) {
    int c = m / 75, q = m - c * 75;
    f32x4 fv = *reinterpret_cast<const f32x4*>(xb + (size_t)c * 7500 + 4 * q);
    int e = 4 * q;
    int t = e / 25, v = e - t * 25;
    int em = emask(c);
    #pragma unroll
    for (int i2 = 0; i2 < 4; ++i2) {
      sm.xs[c * XROW + (((t << 5) + v) ^ em)] = tobf(fv[i2]);
      if (++v == 25) { v = 0; ++t; }
    }
  }
}

// one t, one wh: register-chained stage-A -> stage-B (R3/R6-verified mapping)
static __device__ __forceinline__ void compute_t(
    const bf16_t* xs, const Frags& F, int t, int wh, f32x4& acc0, f32x4& acc1) {
  bf16x8 xf[4];
  #pragma unroll
  for (int q = 0; q < 4; ++q)
    xf[q] = *reinterpret_cast<const bf16x8*>(xs + F.fK[q] + ((t << 5) ^ F.fS5[q]));
  acc0 = f32x4{0.f, 0.f, 0.f, 0.f};
  acc1 = f32x4{0.f, 0.f, 0.f, 0.f};
  #pragma unroll
  for (int k = 0; k < 3; ++k) {
    #pragma unroll
    for (int ch = 0; ch < 2; ++ch) {
      f32x4 zero = {0.f, 0.f, 0.f, 0.f};
      f32x4 dP = __builtin_amdgcn_mfma_f32_16x16x32_bf16(xf[ch * 2 + 0], F.afrag[k][wh], zero, 0, 0, 0);
      f32x4 dQ = __builtin_amdgcn_mfma_f32_16x16x32_bf16(xf[ch * 2 + 1], F.afrag[k][wh], zero, 0, 0, 0);
      bf16x8 zf;
      zf[0] = tobf(dP[0]); zf[1] = tobf(dP[1]); zf[2] = tobf(dP[2]); zf[3] = tobf(dP[3]);
      zf[4] = tobf(dQ[0]); zf[5] = tobf(dQ[1]); zf[6] = tobf(dQ[2]); zf[7] = tobf(dQ[3]);
      if (ch == 0)
        acc0 = __builtin_amdgcn_mfma_f32_16x16x32_bf16(F.wfrag[k * 2 + ch], zf, acc0, 0, 0, 0);
      else
        acc1 = __builtin_amdgcn_mfma_f32_16x16x32_bf16(F.wfrag[k * 2 + ch], zf, acc1, 0, 0, 0);
    }
  }
}

// ---------------------------------------------------------------------------
// K1: stats-only pass -> per-block channel partials, contiguous layout.
// ---------------------------------------------------------------------------
__global__ __launch_bounds__(256, 3) void k1_stats(
    const float* __restrict__ x, const float* __restrict__ A,
    const float* __restrict__ W, const float* __restrict__ b,
    float* __restrict__ part) {
  __shared__ __align__(16) SmemU sm;
  __shared__ float stats[2][64];

  const int bid = (blockIdx.x & 7) * (NBLK / 8) + (blockIdx.x >> 3);  // bijective
  const int n = bid / NTILE;
  const int t0 = (bid - n * NTILE) * TT;
  const int tid = threadIdx.x;
  const int lane = tid & 63;
  const int wv = tid >> 6;
  const int l15 = lane & 15;
  const int lg = lane >> 4;

  stage_wa(A, W, sm, tid);
  __syncthreads();
  Frags F;
  read_frags(sm, b, wv, l15, lg, F);
  __syncthreads();                 // all frag reads done before xs overwrite
  stage_x(x, sm, n, t0, tid);
  __syncthreads();

  float lsum[4] = {0.f, 0.f, 0.f, 0.f}, lsq[4] = {0.f, 0.f, 0.f, 0.f};
  const int w_lo = l15, w_hi = 16 + l15;

  #pragma unroll 2
  for (int t = 0; t < TT; ++t) {
    #pragma unroll
    for (int wh = 0; wh < 2; ++wh) {
      f32x4 acc0, acc1;
      compute_t(sm.xs, F, t, wh, acc0, acc1);
      const int w = wh ? w_hi : w_lo;
      if (w < V_) {
        #pragma unroll
        for (int r = 0; r < 4; ++r) {
          float val = acc0[r] + acc1[r] + F.bs[r];
          lsum[r] += val;
          lsq[r] += val * val;
        }
      }
    }
  }

  #pragma unroll
  for (int d = 1; d < 16; d <<= 1) {
    #pragma unroll
    for (int r = 0; r < 4; ++r) {
      lsum[r] += __shfl_xor(lsum[r], d);
      lsq[r]  += __shfl_xor(lsq[r], d);
    }
  }
  if (l15 == 0) {
    #pragma unroll
    for (int r = 0; r < 4; ++r) {
      stats[0][F.obase + r] = lsum[r];
      stats[1][F.obase + r] = lsq[r];
    }
  }
  __syncthreads();
  if (tid < 128) part[(size_t)bid * 128 + tid] = stats[tid >> 6][tid & 63];
}

// ---------------------------------------------------------------------------
// K2: reduce partials -> per-channel scale/shift
// ---------------------------------------------------------------------------
__global__ __launch_bounds__(256) void k2_stats(
    const float* __restrict__ part,
    const float* __restrict__ gamma, const float* __restrict__ beta,
    float* __restrict__ ss) {
  const int o = blockIdx.x;
  const int tid = threadIdx.x;
  double s = 0.0, q = 0.0;
  for (int i = tid; i < NBLK; i += 256) {
    s += (double)part[(size_t)i * 128 + o];
    q += (double)part[(size_t)i * 128 + 64 + o];
  }
  __shared__ double sd[256], qd[256];
  sd[tid] = s; qd[tid] = q;
  __syncthreads();
  for (int step = 128; step > 0; step >>= 1) {
    if (tid < step) { sd[tid] += sd[tid + step]; qd[tid] += qd[tid + step]; }
    __syncthreads();
  }
  if (tid == 0) {
    const double cnt = 480000.0;
    double mean = sd[0] / cnt;
    double var = qd[0] / cnt - mean * mean;
    float inv = rsqrtf((float)var + EPS_);
    float sc = gamma[o] * inv;
    float sh = beta[o] - (float)mean * sc;
    ss[2 * o] = sc;
    ss[2 * o + 1] = sh;
  }
}

// ---------------------------------------------------------------------------
// K3: recompute y, apply BN + residual (x from LDS, bf16) + relu, store out.
// ---------------------------------------------------------------------------
__global__ __launch_bounds__(256, 3) void k3_apply(
    const float* __restrict__ x, const float* __restrict__ A,
    const float* __restrict__ W, const float* __restrict__ b,
    const float* __restrict__ ss, float* __restrict__ out) {
  __shared__ __align__(16) SmemU sm;

  const int bid = (blockIdx.x & 7) * (NBLK / 8) + (blockIdx.x >> 3);  // bijective
  const int n = bid / NTILE;
  const int t0 = (bid - n * NTILE) * TT;
  const int tid = threadIdx.x;
  const int lane = tid & 63;
  const int wv = tid >> 6;
  const int l15 = lane & 15;
  const int lg = lane >> 4;

  stage_wa(A, W, sm, tid);
  __syncthreads();
  Frags F;
  read_frags(sm, b, wv, l15, lg, F);
  __syncthreads();
  stage_x(x, sm, n, t0, tid);

  float sc[4], sh[4];
  #pragma unroll
  for (int r = 0; r < 4; ++r) {
    sc[r] = ss[2 * (F.obase + r)];
    sh[r] = ss[2 * (F.obase + r) + 1];
  }
  __syncthreads();

  float* ob = out + (size_t)n * 480000 + (size_t)t0 * 25;
  const int w_lo = l15, w_hi = 16 + l15;

  #pragma unroll 2
  for (int t = 0; t < TT; ++t) {
    #pragma unroll
    for (int wh = 0; wh < 2; ++wh) {
      f32x4 acc0, acc1;
      compute_t(sm.xs, F, t, wh, acc0, acc1);
      const int w = wh ? w_hi : w_lo;
      if (w < V_) {
        #pragma unroll
        for (int r = 0; r < 4; ++r) {
          const int o = F.obase + r;
          float val = acc0[r] + acc1[r] + F.bs[r];
          float xr = (float)sm.xs[o * XROW + (((t << 5) + w) ^ emask(o))];
          ob[(size_t)o * 7500 + t * 25 + w] = fmaxf(sc[r] * val + sh[r] + xr, 0.f);
        }
      }
    }
  }
}

extern "C" void kernel_launch(void* const* d_in, const int* in_sizes, int n_in,
                              void* d_out, int out_size, void* d_ws, size_t ws_size,
                              hipStream_t stream) {
  const float* x     = (const float*)d_in[0];
  const float* A     = (const float*)d_in[1];
  const float* W     = (const float*)d_in[2];
  const float* b     = (const float*)d_in[3];
  const float* gamma = (const float*)d_in[4];
  const float* beta  = (const float*)d_in[5];
  float* out = (float*)d_out;

  float* part = (float*)d_ws;                // NBLK*128 floats (contiguous per block)
  float* ss   = part + (size_t)NBLK * 128;   // 128 floats

  k1_stats<<<NBLK, 256, 0, stream>>>(x, A, W, b, part);
  k2_stats<<<64, 256, 0, stream>>>(part, gamma, beta, ss);
  k3_apply<<<NBLK, 256, 0, stream>>>(x, A, W, b, ss, out);
}